// Round 3
// baseline (6491.573 us; speedup 1.0000x reference)
//
#include <hip/hip_runtime.h>
#include <hip/hip_bf16.h>

// ---------------------------------------------------------------------------
// BiRNN: x[64,1024,512] f32 in, y[64,1024,1024]+h[2,64,512] f32 out. H=512.
// Internal compute in bf16 MFMA (threshold is 2% of ref max -> ample room).
//   Phase 0: convert x, Wih, Whh, fcW, h0 to bf16 in ws.
//   Phase 1: UH[d][t][m][n] = xb(,time-flip for bw) @ Wihb^T + (bih+bhh)
//   Phase 2: h_t = tanh(UH[d][t] + h_{t-1} @ Whhb^T) IN PLACE into UH[d][t].
//            128 persistent single-wave blocks, Whh register-resident,
//            per-group atomic counter sync.
//   Phase 3: y = UH @ fcWb^T + fcb -> f32 d_out[m][t][d*512+n]; h_out f32.
// ws (u16 elems): UH 67108864 | Xb 33554432 | 6 x W 262144 | h0b 65536 | flags
// total ~195.3 MiB.
// ---------------------------------------------------------------------------

typedef unsigned short u16;
using frag8 = __attribute__((ext_vector_type(8))) short;
using f32x4 = __attribute__((ext_vector_type(4))) float;

#define SEQ 33554432ull          // 1024*64*512 elems (one direction slab)
#define UTOT 67108864ull         // 2*SEQ

__device__ __forceinline__ float bf2f(u16 u){
  union { unsigned i; float f; } v; v.i = ((unsigned)u) << 16; return v.f;
}
__device__ __forceinline__ u16 f2bf(float f){
  union { float f; unsigned i; } v; v.f = f;
  unsigned r = v.i + 0x7FFFu + ((v.i >> 16) & 1u);
  return (u16)(r >> 16);
}
__device__ __forceinline__ float tanh_fast(float x){
  float e = __expf(2.0f * x);                 // e>=0; inf saturates fine
  return 1.0f - __fdividef(2.0f, e + 1.0f);
}
__device__ __forceinline__ void async16(void* lds, const void* g){
  __builtin_amdgcn_global_load_lds((const __attribute__((address_space(1))) void*)g,
                                   (__attribute__((address_space(3))) void*)lds,
                                   16, 0, 0);
}

// --------------------------- f32 -> bf16 convert ---------------------------
__global__ __launch_bounds__(256) void cvt_kernel(const float* __restrict__ src,
                                                  u16* __restrict__ dst, int n4)
{
  int i = blockIdx.x * 256 + threadIdx.x;
  if (i < n4) {
    float4 v = ((const float4*)src)[i];
    ushort4 o;
    o.x = f2bf(v.x); o.y = f2bf(v.y); o.z = f2bf(v.z); o.w = f2bf(v.w);
    ((ushort4*)dst)[i] = o;
  }
}

// ---------------------------------------------------------------------------
// GEMM: C[r][n] = A[r][:] @ W^T[:][n] + bias, A bf16 65536x512 per dir.
// mode 0: A row r = m*1024+t (x layout); store bf16 UH[((d*1024+tu)*64+m)*512+n],
//         tu = d ? 1023-t : t.
// mode 1: A row r' = t*64+m (UH layout); store f32 y[(m*1024+t)*1024+d*512+n].
// ---------------------------------------------------------------------------
__global__ __launch_bounds__(256, 2) void gemm_kernel(
    const u16* __restrict__ A0, const u16* __restrict__ A1,
    const u16* __restrict__ W0, const u16* __restrict__ W1,
    const float* __restrict__ ba0, const float* __restrict__ bb0,
    const float* __restrict__ ba1, const float* __restrict__ bb1,
    void* __restrict__ outv, int mode)
{
  __shared__ u16 As[2][128 * 32];
  __shared__ u16 Bs[2][128 * 32];

  int bx = blockIdx.x;
  int nt = bx & 3, mt = (bx >> 2) & 511, d = bx >> 11;
  const u16* A   = d ? A1 : A0;
  const u16* W   = d ? W1 : W0;
  const float* ba = d ? ba1 : ba0;
  const float* bb = d ? bb1 : bb0;
  int rbase = mt * 128, nbase = nt * 128;

  int tid = threadIdx.x, w = tid >> 6, l = tid & 63;
  int lr = l & 15, lq = l >> 4;
  int crow = l >> 2;           // 0..15 within a 16-row chunk
  int koff = (l & 3) * 8;      // elems within the 32-k row
  int m0 = (w >> 1) * 64, n0 = (w & 1) * 64;

  f32x4 acc[4][4] = {};

  auto stage = [&](int buf, int kc) {
    #pragma unroll
    for (int j = 0; j < 2; ++j) {
      int c = w * 2 + j;                       // 0..7, wave-uniform
      const u16* ga = A + (size_t)(rbase + c * 16 + crow) * 512 + kc * 32 + koff;
      async16(&As[buf][c * 512], ga);
      const u16* gb = W + (size_t)(nbase + c * 16 + crow) * 512 + kc * 32 + koff;
      async16(&Bs[buf][c * 512], gb);
    }
  };

  stage(0, 0);
  __syncthreads();
  for (int kc = 0; kc < 16; ++kc) {
    int buf = kc & 1;
    if (kc < 15) stage(buf ^ 1, kc + 1);
    frag8 af[4], bfv[4];
    #pragma unroll
    for (int i = 0; i < 4; ++i) {
      af[i]  = *(const frag8*)&As[buf][(m0 + i * 16 + lr) * 32 + lq * 8];
      bfv[i] = *(const frag8*)&Bs[buf][(n0 + i * 16 + lr) * 32 + lq * 8];
    }
    #pragma unroll
    for (int mi = 0; mi < 4; ++mi)
      #pragma unroll
      for (int ni = 0; ni < 4; ++ni)
        acc[mi][ni] = __builtin_amdgcn_mfma_f32_16x16x32_bf16(af[mi], bfv[ni], acc[mi][ni], 0, 0, 0);
    __syncthreads();
  }

  // epilogue: D layout row=(lq*4+rr), col=lr
  #pragma unroll
  for (int ni = 0; ni < 4; ++ni) {
    int n = nbase + n0 + ni * 16 + lr;
    float bias = ba[n] + (bb ? bb[n] : 0.0f);
    #pragma unroll
    for (int mi = 0; mi < 4; ++mi) {
      #pragma unroll
      for (int rr = 0; rr < 4; ++rr) {
        int r = rbase + m0 + mi * 16 + lq * 4 + rr;
        float v = acc[mi][ni][rr] + bias;
        if (mode == 0) {
          int m = r >> 10, t = r & 1023;
          int tu = d ? (1023 - t) : t;
          ((u16*)outv)[((size_t)((d * 1024 + tu) * 64 + m)) * 512 + n] = f2bf(v);
        } else {
          int t = r >> 6, m = r & 63;
          ((float*)outv)[((size_t)m * 1024 + t) * 1024 + d * 512 + n] = v;
        }
      }
    }
  }
}

// ---------------------------------------------------------------------------
// Recurrence: 128 blocks x 64 threads (1 wave each; trivially co-resident).
// bid = p*8 + G; G=(d*4+g) is the sync group (16 waves, one per 32-col chunk
// p). Whhb[32x512] slice in VGPRs. UH[d][t][m][n]: read own U slice, then
// overwrite the same elements with h_t. Counter: +1 release after store,
// wait >= 16*t acquire before reading h_{t-1}.
// ---------------------------------------------------------------------------
__global__ __launch_bounds__(64, 1) void rnn_kernel(
    const u16* __restrict__ h0b,
    const u16* __restrict__ Whh0, const u16* __restrict__ Whh1,
    u16* __restrict__ UH, float* __restrict__ tail, int* __restrict__ flags)
{
  int bid = blockIdx.x;
  int G = bid & 7;
  int p = bid >> 3;
  int d = G >> 2, g = G & 3;
  int l = threadIdx.x;
  int lr = l & 15, lq = l >> 4;

  const u16* Whh = d ? Whh1 : Whh0;

  // B-frags: n = p*32 + tl*16 + lr ; k = ks*32 + lq*8  (B[k][n] = Whh[n][k])
  frag8 Bf[2][16];
  #pragma unroll
  for (int tl = 0; tl < 2; ++tl)
    #pragma unroll
    for (int ks = 0; ks < 16; ++ks)
      Bf[tl][ks] = *(const frag8*)(Whh + (size_t)(p * 32 + tl * 16 + lr) * 512 + ks * 32 + lq * 8);

  int* cnt = flags + G * 32;   // 128B-spaced counters

  // A-frag (h_{t-1}): m = lr (batch row within group), k = ks*32 + lq*8
  const u16* h0p = h0b + (size_t)(d * 64 + g * 16 + lr) * 512 + lq * 8;
  const u16* HbA = UH + ((size_t)d * 65536 + (size_t)(g * 16 + lr)) * 512 + lq * 8; // + t*32768
  // C rows: m = g*16 + lq*4 + rr; cols n = p*32 + tl*16 + lr
  u16* Up = UH + ((size_t)d * 65536 + (size_t)(g * 16 + lq * 4)) * 512 + p * 32 + lr; // + t*32768

  for (int t = 0; t < 1024; ++t) {
    // Prefetch own U slice (these elems are only ever touched by this wave
    // at step t, so reading before the wait is race-free).
    float uv[2][4];
    {
      const u16* up = Up + (size_t)t * 32768;
      #pragma unroll
      for (int tl = 0; tl < 2; ++tl)
        #pragma unroll
        for (int rr = 0; rr < 4; ++rr)
          uv[tl][rr] = bf2f(up[(size_t)rr * 512 + tl * 16]);
    }
    if (t > 0) {
      int target = 16 * t;
      while (__hip_atomic_load(cnt, __ATOMIC_ACQUIRE, __HIP_MEMORY_SCOPE_AGENT) < target) {}
    }
    f32x4 c0, c1;
    #pragma unroll
    for (int rr = 0; rr < 4; ++rr) { c0[rr] = uv[0][rr]; c1[rr] = uv[1][rr]; }

    const u16* ap = (t == 0) ? h0p : (HbA + (size_t)(t - 1) * 32768);
    #pragma unroll
    for (int ks = 0; ks < 16; ++ks) {
      frag8 a = *(const frag8*)(ap + ks * 32);
      c0 = __builtin_amdgcn_mfma_f32_16x16x32_bf16(a, Bf[0][ks], c0, 0, 0, 0);
      c1 = __builtin_amdgcn_mfma_f32_16x16x32_bf16(a, Bf[1][ks], c1, 0, 0, 0);
    }

    u16* sp = Up + (size_t)t * 32768;
    #pragma unroll
    for (int rr = 0; rr < 4; ++rr) {
      float v0 = tanh_fast(c0[rr]);
      float v1 = tanh_fast(c1[rr]);
      sp[(size_t)rr * 512]      = f2bf(v0);
      sp[(size_t)rr * 512 + 16] = f2bf(v1);
      if (t == 1023) {
        size_t tb = (size_t)(d * 64 + g * 16 + lq * 4 + rr) * 512 + p * 32 + lr;
        tail[tb]      = v0;
        tail[tb + 16] = v1;
      }
    }
    if (l == 0)
      __hip_atomic_fetch_add(cnt, 1, __ATOMIC_RELEASE, __HIP_MEMORY_SCOPE_AGENT);
  }
}

// ---------------------------------------------------------------------------
extern "C" void kernel_launch(void* const* d_in, const int* in_sizes, int n_in,
                              void* d_out, int out_size, void* d_ws, size_t ws_size,
                              hipStream_t stream)
{
  const float* x     = (const float*)d_in[0];
  const float* h0    = (const float*)d_in[1];
  const float* fwWih = (const float*)d_in[2];
  const float* fwWhh = (const float*)d_in[3];
  const float* fwbih = (const float*)d_in[4];
  const float* fwbhh = (const float*)d_in[5];
  const float* fwfcW = (const float*)d_in[6];
  const float* fwfcb = (const float*)d_in[7];
  const float* bwWih = (const float*)d_in[8];
  const float* bwWhh = (const float*)d_in[9];
  const float* bwbih = (const float*)d_in[10];
  const float* bwbhh = (const float*)d_in[11];
  const float* bwfcW = (const float*)d_in[12];
  const float* bwfcb = (const float*)d_in[13];

  float* out = (float*)d_out;

  u16* UH    = (u16*)d_ws;
  u16* Xb    = UH + UTOT;
  u16* Wihb0 = Xb + SEQ;            // x is 33554432 elems
  u16* Wihb1 = Wihb0 + 262144;
  u16* Whhb0 = Wihb1 + 262144;
  u16* Whhb1 = Whhb0 + 262144;
  u16* fcWb0 = Whhb1 + 262144;
  u16* fcWb1 = fcWb0 + 262144;
  u16* h0b   = fcWb1 + 262144;
  int* flags = (int*)(h0b + 65536);

  hipMemsetAsync(flags, 0, 1024, stream);

  // Phase 0: f32 -> bf16 conversions
  cvt_kernel<<<32768, 256, 0, stream>>>(x, Xb, 8388608);
  cvt_kernel<<<256, 256, 0, stream>>>(fwWih, Wihb0, 65536);
  cvt_kernel<<<256, 256, 0, stream>>>(bwWih, Wihb1, 65536);
  cvt_kernel<<<256, 256, 0, stream>>>(fwWhh, Whhb0, 65536);
  cvt_kernel<<<256, 256, 0, stream>>>(bwWhh, Whhb1, 65536);
  cvt_kernel<<<256, 256, 0, stream>>>(fwfcW, fcWb0, 65536);
  cvt_kernel<<<256, 256, 0, stream>>>(bwfcW, fcWb1, 65536);
  cvt_kernel<<<64, 256, 0, stream>>>(h0, h0b, 16384);

  // Phase 1: UH = xb @ Wihb^T + (bih+bhh), both dirs (bw time-flip at store)
  gemm_kernel<<<4096, 256, 0, stream>>>(Xb, Xb, Wihb0, Wihb1,
                                        fwbih, fwbhh, bwbih, bwbhh, UH, 0);

  // Phase 2: recurrence, h stored in place into UH
  rnn_kernel<<<128, 64, 0, stream>>>(h0b, Whhb0, Whhb1, UH,
                                     out + 67108864ull, flags);

  // Phase 3: y = UH @ fcWb^T + fcb  (f32 output)
  gemm_kernel<<<4096, 256, 0, stream>>>(UH, UH + SEQ, fcWb0, fcWb1,
                                        fwfcb, nullptr, bwfcb, nullptr, out, 1);
}